// Round 1
// baseline (128.913 us; speedup 1.0000x reference)
//
#include <hip/hip_runtime.h>

typedef _Float16 f16;
typedef f16 f16x8 __attribute__((ext_vector_type(8)));
typedef f16 f16x4 __attribute__((ext_vector_type(4)));
typedef float f32x4 __attribute__((ext_vector_type(4)));

constexpr float ATT_SCALE = 0.17677669529663687f; // 1/sqrt(32)

// ---------------- multi-scale avg pool (k=3,5,7; s=1; p=1,2,3; count_include_pad) ----
__global__ __launch_bounds__(256) void pool_kernel(const float* __restrict__ y,
                                                   float* __restrict__ pooled)
{
    int bc = blockIdx.x;                 // b*256 + c
    const float* plane = y + (size_t)bc * 1024;
    __shared__ float p[38][38];          // 32 + 2*3 halo
    int t = threadIdx.x;
    for (int i = t; i < 38 * 38; i += 256) (&p[0][0])[i] = 0.f;
    __syncthreads();
    for (int i = t; i < 1024; i += 256) p[(i >> 5) + 3][(i & 31) + 3] = plane[i];
    __syncthreads();
    int b = bc >> 8, c = bc & 255;
    for (int i = t; i < 1024; i += 256) {
        int r = (i >> 5) + 3, cc = (i & 31) + 3;
        float s3 = 0.f;
        #pragma unroll
        for (int dr = -1; dr <= 1; ++dr)
            #pragma unroll
            for (int dc = -1; dc <= 1; ++dc) s3 += p[r + dr][cc + dc];
        float r5 = 0.f;
        #pragma unroll
        for (int dc = -2; dc <= 2; ++dc) r5 += p[r - 2][cc + dc] + p[r + 2][cc + dc];
        #pragma unroll
        for (int dr = -1; dr <= 1; ++dr) r5 += p[r + dr][cc - 2] + p[r + dr][cc + 2];
        float r7 = 0.f;
        #pragma unroll
        for (int dc = -3; dc <= 3; ++dc) r7 += p[r - 3][cc + dc] + p[r + 3][cc + dc];
        #pragma unroll
        for (int dr = -2; dr <= 2; ++dr) r7 += p[r + dr][cc - 3] + p[r + dr][cc + 3];
        float s5 = s3 + r5, s7 = s5 + r7;
        float val = s3 * (1.f / 9.f) + s5 * (1.f / 25.f) + s7 * (1.f / 49.f);
        pooled[((size_t)b * 1024 + i) * 256 + c] = val;   // [b][n][c]
    }
}

// ---------------- LayerNorm over C=256, one row per wave, f16 out ----------------
__global__ __launch_bounds__(256) void ln_kernel(const float* __restrict__ pooled,
                                                 const float* __restrict__ g,
                                                 const float* __restrict__ bta,
                                                 f16* __restrict__ yfln)
{
    int w = threadIdx.x >> 6, lane = threadIdx.x & 63;
    int row = blockIdx.x * 4 + w;
    float4 v = ((const float4*)(pooled + (size_t)row * 256))[lane];
    float s  = v.x + v.y + v.z + v.w;
    float s2 = v.x * v.x + v.y * v.y + v.z * v.z + v.w * v.w;
    #pragma unroll
    for (int off = 32; off; off >>= 1) { s += __shfl_xor(s, off); s2 += __shfl_xor(s2, off); }
    float mu = s * (1.f / 256.f);
    float var = s2 * (1.f / 256.f) - mu * mu;
    float rstd = rsqrtf(var + 1e-5f);
    float4 gg = ((const float4*)g)[lane];
    float4 bb = ((const float4*)bta)[lane];
    f16x4 o;
    o[0] = (f16)((v.x - mu) * rstd * gg.x + bb.x);
    o[1] = (f16)((v.y - mu) * rstd * gg.y + bb.y);
    o[2] = (f16)((v.z - mu) * rstd * gg.z + bb.z);
    o[3] = (f16)((v.w - mu) * rstd * gg.w + bb.w);
    *(f16x4*)(yfln + (size_t)row * 256 + lane * 4) = o;
}

// ---------------- transpose+cast x: [B,C,N] f32 -> [B,N,C] f16 ----------------
__global__ __launch_bounds__(256) void xt_kernel(const float* __restrict__ x,
                                                 f16* __restrict__ xT)
{
    int bid = blockIdx.x;
    int b = bid >> 8, ct = (bid >> 5) & 7, nt = bid & 31;
    __shared__ float tile[32][33];
    int rr = threadIdx.x >> 5, j = threadIdx.x & 31;
    #pragma unroll
    for (int r = rr; r < 32; r += 8)
        tile[r][j] = x[((size_t)b * 256 + ct * 32 + r) * 1024 + nt * 32 + j];
    __syncthreads();
    #pragma unroll
    for (int r = rr; r < 32; r += 8)
        xT[((size_t)b * 1024 + nt * 32 + r) * 256 + ct * 32 + j] = (f16)tile[j][r];
}

// ---------------- weight casts ----------------
__global__ __launch_bounds__(256) void wcast_kernel(const float* __restrict__ Wq,
                                                    const float* __restrict__ Wkv,
                                                    const float* __restrict__ Wp,
                                                    f16* __restrict__ wq16,
                                                    f16* __restrict__ wkv16,
                                                    f16* __restrict__ wp16)
{
    int i = blockIdx.x * 256 + threadIdx.x;   // grid 512 -> 131072 threads
    if (i < 65536) { wq16[i] = (f16)Wq[i]; wp16[i] = (f16)Wp[i]; }
    wkv16[i] = (f16)Wkv[i];
}

// ---------------- Q projection: [2048,256] @ Wq^T, scale folded, -> q16[b][h][n][d] ----
__global__ __launch_bounds__(256) void qgemm_kernel(const f16* __restrict__ A,
                                                    const f16* __restrict__ Bm,
                                                    f16* __restrict__ q16)
{
    int mt = blockIdx.x >> 2, nt = blockIdx.x & 3;
    int w = threadIdx.x >> 6, lane = threadIdx.x & 63;
    int l15 = lane & 15, lhi = lane >> 4;
    int row0 = mt * 64 + w * 16;
    f32x4 acc[4] = {};
    for (int k0 = 0; k0 < 256; k0 += 32) {
        f16x8 a = *(const f16x8*)(A + (size_t)(row0 + l15) * 256 + k0 + lhi * 8);
        #pragma unroll
        for (int j = 0; j < 4; ++j) {
            f16x8 bf = *(const f16x8*)(Bm + (size_t)(nt * 64 + j * 16 + l15) * 256 + k0 + lhi * 8);
            acc[j] = __builtin_amdgcn_mfma_f32_16x16x32_f16(a, bf, acc[j], 0, 0, 0);
        }
    }
    #pragma unroll
    for (int j = 0; j < 4; ++j) {
        int col = nt * 64 + j * 16 + l15;
        int h = col >> 5, d = col & 31;
        #pragma unroll
        for (int r = 0; r < 4; ++r) {
            int row = row0 + 4 * lhi + r;
            int b = row >> 10, n = row & 1023;
            q16[(((size_t)(b * 8 + h)) * 1024 + n) * 32 + d] = (f16)(acc[j][r] * ATT_SCALE);
        }
    }
}

// ---------------- KV projection -> k16[b][h][n][d], vT16[b][h][d][n] ----------------
__global__ __launch_bounds__(256) void kvgemm_kernel(const f16* __restrict__ A,
                                                     const f16* __restrict__ Bm,
                                                     f16* __restrict__ k16,
                                                     f16* __restrict__ vT16)
{
    int mt = blockIdx.x >> 3, nt = blockIdx.x & 7;
    int w = threadIdx.x >> 6, lane = threadIdx.x & 63;
    int l15 = lane & 15, lhi = lane >> 4;
    int row0 = mt * 64 + w * 16;
    f32x4 acc[4] = {};
    for (int k0 = 0; k0 < 256; k0 += 32) {
        f16x8 a = *(const f16x8*)(A + (size_t)(row0 + l15) * 256 + k0 + lhi * 8);
        #pragma unroll
        for (int j = 0; j < 4; ++j) {
            f16x8 bf = *(const f16x8*)(Bm + (size_t)(nt * 64 + j * 16 + l15) * 256 + k0 + lhi * 8);
            acc[j] = __builtin_amdgcn_mfma_f32_16x16x32_f16(a, bf, acc[j], 0, 0, 0);
        }
    }
    #pragma unroll
    for (int j = 0; j < 4; ++j) {
        int col = nt * 64 + j * 16 + l15;
        #pragma unroll
        for (int r = 0; r < 4; ++r) {
            int row = row0 + 4 * lhi + r;
            int b = row >> 10, n = row & 1023;
            float v = acc[j][r];
            if (col < 256) {
                int h = col >> 5, d = col & 31;
                k16[(((size_t)(b * 8 + h)) * 1024 + n) * 32 + d] = (f16)v;
            } else {
                int c2 = col - 256, h = c2 >> 5, d = c2 & 31;
                vT16[(((size_t)(b * 8 + h)) * 32 + d) * 1024 + n] = (f16)v;
            }
        }
    }
}

// ---------------- exact-count pivot search via ballot bisection ----------------
__device__ __forceinline__ float find_thresh(const float* s, float lo, float hi, int k)
{
    for (int it = 0; it < 26; ++it) {
        float mid = 0.5f * (lo + hi);
        if (!(mid > lo && mid < hi)) break;
        int cnt = 0;
        #pragma unroll
        for (int i = 0; i < 16; ++i)
            cnt += (int)__popcll(__ballot(s[i] >= mid));
        if (cnt == k) return mid;
        if (cnt > k) lo = mid; else hi = mid;
    }
    return lo;   // count_ge(lo) >= k (at worst includes a near-tie extra)
}

// ---------------- fused attention: S=QK^T, top-k thresholds, combined weights, PV ----
__global__ __launch_bounds__(256) void attn_kernel(const f16* __restrict__ q16,
                                                   const f16* __restrict__ k16,
                                                   const f16* __restrict__ vT16,
                                                   const float* __restrict__ a1p,
                                                   const float* __restrict__ a2p,
                                                   f16* __restrict__ oat)
{
    __shared__ float Sb[16 * 1024];      // 64 KB, col-swizzled
    int bid = blockIdx.x;
    int bh = bid >> 6, rb = bid & 63;
    int row0 = rb * 16;
    int w = threadIdx.x >> 6, lane = threadIdx.x & 63;
    int l15 = lane & 15, lhi = lane >> 4;
    const f16* Qb = q16 + (size_t)bh * 1024 * 32;
    const f16* Kb = k16 + (size_t)bh * 1024 * 32;
    const f16* Vb = vT16 + (size_t)bh * 32 * 1024;

    // phase 1: S = Q K^T (scale already folded into q16)
    {
        f16x8 a = *(const f16x8*)(Qb + (size_t)(row0 + l15) * 32 + lhi * 8);
        for (int j = 0; j < 16; ++j) {
            int c0 = (w * 16 + j) * 16;
            f16x8 bf = *(const f16x8*)(Kb + (size_t)(c0 + l15) * 32 + lhi * 8);
            f32x4 z = {0.f, 0.f, 0.f, 0.f};
            f32x4 d = __builtin_amdgcn_mfma_f32_16x16x32_f16(a, bf, z, 0, 0, 0);
            #pragma unroll
            for (int r = 0; r < 4; ++r) {
                int rw = 4 * lhi + r;
                Sb[rw * 1024 + ((c0 + l15) ^ ((rw & 7) << 2))] = d[r];
            }
        }
    }
    __syncthreads();

    // phase 2: per-row thresholds + combined softmax weights (in place)
    float c_a1 = a1p[0], c_a2 = a2p[0];
    for (int rr = 0; rr < 4; ++rr) {
        int r = w * 4 + rr;
        int sw = (r & 7) << 2;
        float s[16];
        #pragma unroll
        for (int i = 0; i < 16; ++i) s[i] = Sb[r * 1024 + ((lane + 64 * i) ^ sw)];
        float mx = s[0], mn = s[0];
        #pragma unroll
        for (int i = 1; i < 16; ++i) { mx = fmaxf(mx, s[i]); mn = fminf(mn, s[i]); }
        #pragma unroll
        for (int off = 32; off; off >>= 1) {
            mx = fmaxf(mx, __shfl_xor(mx, off));
            mn = fminf(mn, __shfl_xor(mn, off));
        }
        float T1 = find_thresh(s, mn, mx, 512);   // kk1 = 1024/2
        float T2 = find_thresh(s, T1, mx, 341);   // kk2 = int(1024/3)
        float p[16];
        float l1 = 0.f, l2 = 0.f;
        #pragma unroll
        for (int i = 0; i < 16; ++i) {
            float e = __expf(s[i] - mx);
            p[i] = e;
            if (s[i] >= T1) l1 += e;
            if (s[i] >= T2) l2 += e;
        }
        #pragma unroll
        for (int off = 32; off; off >>= 1) { l1 += __shfl_xor(l1, off); l2 += __shfl_xor(l2, off); }
        float c1 = c_a1 / l1, c2 = c_a2 / l2;
        #pragma unroll
        for (int i = 0; i < 16; ++i) {
            float wt = (s[i] >= T1 ? c1 : 0.f) + (s[i] >= T2 ? c2 : 0.f);
            Sb[r * 1024 + ((lane + 64 * i) ^ sw)] = p[i] * wt;
        }
    }
    __syncthreads();

    // phase 3: out = W V, m-range split across 4 waves
    f32x4 acc0 = {}, acc1 = {};
    int swl = (l15 & 7) << 2;
    for (int ks = 0; ks < 8; ++ks) {
        int m0 = w * 256 + ks * 32 + lhi * 8;
        float4 ch0 = *(const float4*)&Sb[l15 * 1024 + ((m0)     ^ swl)];
        float4 ch1 = *(const float4*)&Sb[l15 * 1024 + ((m0 + 4) ^ swl)];
        f16x8 af;
        af[0] = (f16)ch0.x; af[1] = (f16)ch0.y; af[2] = (f16)ch0.z; af[3] = (f16)ch0.w;
        af[4] = (f16)ch1.x; af[5] = (f16)ch1.y; af[6] = (f16)ch1.z; af[7] = (f16)ch1.w;
        f16x8 b0 = *(const f16x8*)(Vb + (size_t)(l15) * 1024 + m0);
        f16x8 b1 = *(const f16x8*)(Vb + (size_t)(16 + l15) * 1024 + m0);
        acc0 = __builtin_amdgcn_mfma_f32_16x16x32_f16(af, b0, acc0, 0, 0, 0);
        acc1 = __builtin_amdgcn_mfma_f32_16x16x32_f16(af, b1, acc1, 0, 0, 0);
    }
    __syncthreads();
    #pragma unroll
    for (int r = 0; r < 4; ++r) {
        int rw = 4 * lhi + r;
        Sb[w * 512 + rw * 32 + l15]      = acc0[r];
        Sb[w * 512 + rw * 32 + 16 + l15] = acc1[r];
    }
    __syncthreads();
    int b = bh >> 3, h = bh & 7;
    for (int o = threadIdx.x; o < 512; o += 256) {
        int r = o >> 5, d = o & 31;
        float v = Sb[o] + Sb[512 + o] + Sb[1024 + o] + Sb[1536 + o];
        oat[((size_t)b * 1024 + row0 + r) * 256 + h * 32 + d] = (f16)v;
    }
}

// ---------------- output projection + bias -> d_out [B,C,32,32] f32 ----------------
__global__ __launch_bounds__(256) void projgemm_kernel(const f16* __restrict__ A,
                                                       const f16* __restrict__ Bm,
                                                       const float* __restrict__ bias,
                                                       float* __restrict__ out)
{
    int mt = blockIdx.x >> 2, nt = blockIdx.x & 3;
    int w = threadIdx.x >> 6, lane = threadIdx.x & 63;
    int l15 = lane & 15, lhi = lane >> 4;
    int row0 = mt * 64 + w * 16;
    f32x4 acc[4] = {};
    for (int k0 = 0; k0 < 256; k0 += 32) {
        f16x8 a = *(const f16x8*)(A + (size_t)(row0 + l15) * 256 + k0 + lhi * 8);
        #pragma unroll
        for (int j = 0; j < 4; ++j) {
            f16x8 bf = *(const f16x8*)(Bm + (size_t)(nt * 64 + j * 16 + l15) * 256 + k0 + lhi * 8);
            acc[j] = __builtin_amdgcn_mfma_f32_16x16x32_f16(a, bf, acc[j], 0, 0, 0);
        }
    }
    #pragma unroll
    for (int j = 0; j < 4; ++j) {
        int col = nt * 64 + j * 16 + l15;
        float bv = bias[col];
        #pragma unroll
        for (int r = 0; r < 4; ++r) {
            int row = row0 + 4 * lhi + r;
            int b = row >> 10, n = row & 1023;
            out[(size_t)b * 262144 + (size_t)col * 1024 + n] = acc[j][r] + bv;
        }
    }
}

extern "C" void kernel_launch(void* const* d_in, const int* in_sizes, int n_in,
                              void* d_out, int out_size, void* d_ws, size_t ws_size,
                              hipStream_t stream)
{
    const float* x     = (const float*)d_in[0];
    const float* y     = (const float*)d_in[1];
    const float* Wq    = (const float*)d_in[2];
    const float* Wkv   = (const float*)d_in[3];
    const float* Wproj = (const float*)d_in[4];
    const float* bproj = (const float*)d_in[5];
    const float* ln_g  = (const float*)d_in[6];
    const float* ln_b  = (const float*)d_in[7];
    const float* a1p   = (const float*)d_in[8];
    const float* a2p   = (const float*)d_in[9];
    float* out = (float*)d_out;

    char* wsb = (char*)d_ws;
    float* pooled = (float*)(wsb);                                   // 2 MB
    f16* yfln  = (f16*)(wsb + ((size_t)2 << 20));                    // 1 MB
    f16* xT    = (f16*)(wsb + ((size_t)3 << 20));                    // 1 MB
    f16* wq16  = (f16*)(wsb + ((size_t)4 << 20));                    // 128 KB
    f16* wkv16 = (f16*)(wsb + ((size_t)4 << 20) + (128 << 10));      // 256 KB
    f16* wp16  = (f16*)(wsb + ((size_t)4 << 20) + (384 << 10));      // 128 KB
    f16* q16   = (f16*)(wsb + ((size_t)4 << 20) + (512 << 10));      // 1 MB
    f16* k16   = (f16*)(wsb + ((size_t)4 << 20) + (512 << 10) + ((size_t)1 << 20));
    f16* vT16  = (f16*)(wsb + ((size_t)4 << 20) + (512 << 10) + ((size_t)2 << 20));
    f16* oat   = (f16*)(wsb + ((size_t)4 << 20) + (512 << 10) + ((size_t)3 << 20));

    pool_kernel<<<512, 256, 0, stream>>>(y, pooled);
    ln_kernel<<<512, 256, 0, stream>>>(pooled, ln_g, ln_b, yfln);
    xt_kernel<<<512, 256, 0, stream>>>(x, xT);
    wcast_kernel<<<512, 256, 0, stream>>>(Wq, Wkv, Wproj, wq16, wkv16, wp16);
    qgemm_kernel<<<128, 256, 0, stream>>>(xT, wq16, q16);
    kvgemm_kernel<<<256, 256, 0, stream>>>(yfln, wkv16, k16, vT16);
    attn_kernel<<<1024, 256, 0, stream>>>(q16, k16, vT16, a1p, a2p, oat);
    projgemm_kernel<<<128, 256, 0, stream>>>(oat, wp16, bproj, out);
}

// Round 2
// 92.602 us; speedup vs baseline: 1.3921x; 1.3921x over previous
//
#include <hip/hip_runtime.h>

typedef _Float16 f16;
typedef f16 f16x8 __attribute__((ext_vector_type(8)));
typedef f16 f16x4 __attribute__((ext_vector_type(4)));
typedef float f32x4 __attribute__((ext_vector_type(4)));

constexpr float ATT_SCALE = 0.17677669529663687f; // 1/sqrt(32)

// ---------------- multi-scale avg pool -> pooled[b][c][n] (coalesced) ----------------
__global__ __launch_bounds__(256) void pool_kernel(const float* __restrict__ y,
                                                   float* __restrict__ pooled)
{
    int bc = blockIdx.x;                 // b*256 + c
    const float* plane = y + (size_t)bc * 1024;
    __shared__ float p[38][38];          // 32 + 2*3 halo
    int t = threadIdx.x;
    for (int i = t; i < 38 * 38; i += 256) (&p[0][0])[i] = 0.f;
    __syncthreads();
    for (int i = t; i < 1024; i += 256) p[(i >> 5) + 3][(i & 31) + 3] = plane[i];
    __syncthreads();
    for (int i = t; i < 1024; i += 256) {
        int r = (i >> 5) + 3, cc = (i & 31) + 3;
        float s3 = 0.f;
        #pragma unroll
        for (int dr = -1; dr <= 1; ++dr)
            #pragma unroll
            for (int dc = -1; dc <= 1; ++dc) s3 += p[r + dr][cc + dc];
        float r5 = 0.f;
        #pragma unroll
        for (int dc = -2; dc <= 2; ++dc) r5 += p[r - 2][cc + dc] + p[r + 2][cc + dc];
        #pragma unroll
        for (int dr = -1; dr <= 1; ++dr) r5 += p[r + dr][cc - 2] + p[r + dr][cc + 2];
        float r7 = 0.f;
        #pragma unroll
        for (int dc = -3; dc <= 3; ++dc) r7 += p[r - 3][cc + dc] + p[r + 3][cc + dc];
        #pragma unroll
        for (int dr = -2; dr <= 2; ++dr) r7 += p[r + dr][cc - 3] + p[r + dr][cc + 3];
        float s5 = s3 + r5, s7 = s5 + r7;
        float val = s3 * (1.f / 9.f) + s5 * (1.f / 25.f) + s7 * (1.f / 49.f);
        pooled[(size_t)bc * 1024 + i] = val;       // [b][c][n] coalesced
    }
}

// ---------------- transposing LayerNorm: pooled[b][c][n] -> yfln[b][n][c] f16 --------
__global__ __launch_bounds__(256) void ln_kernel(const float* __restrict__ pooled,
                                                 const float* __restrict__ g,
                                                 const float* __restrict__ bta,
                                                 f16* __restrict__ yfln)
{
    __shared__ float tile[256][33];
    int bid = blockIdx.x;                // b*32 + ntile
    int b = bid >> 5, n0 = (bid & 31) * 32;
    int t = threadIdx.x;
    int cpart = t & 7;                   // which 4-float chunk of the 32 n's
    #pragma unroll
    for (int r0 = 0; r0 < 8; ++r0) {
        int c = r0 * 32 + (t >> 3);
        float4 v = *(const float4*)(pooled + ((size_t)b * 256 + c) * 1024 + n0 + cpart * 4);
        tile[c][cpart * 4 + 0] = v.x;
        tile[c][cpart * 4 + 1] = v.y;
        tile[c][cpart * 4 + 2] = v.z;
        tile[c][cpart * 4 + 3] = v.w;
    }
    __syncthreads();
    int w = t >> 6, lane = t & 63;
    float gg[4], bb[4];
    #pragma unroll
    for (int j = 0; j < 4; ++j) { gg[j] = g[lane + 64 * j]; bb[j] = bta[lane + 64 * j]; }
    for (int nn = 0; nn < 8; ++nn) {
        int nl = w * 8 + nn;
        float v[4];
        float s = 0.f, s2 = 0.f;
        #pragma unroll
        for (int j = 0; j < 4; ++j) {
            v[j] = tile[lane + 64 * j][nl];
            s += v[j]; s2 += v[j] * v[j];
        }
        #pragma unroll
        for (int off = 32; off; off >>= 1) { s += __shfl_xor(s, off); s2 += __shfl_xor(s2, off); }
        float mu = s * (1.f / 256.f);
        float var = s2 * (1.f / 256.f) - mu * mu;
        float rstd = rsqrtf(var + 1e-5f);
        #pragma unroll
        for (int j = 0; j < 4; ++j)
            yfln[((size_t)b * 1024 + n0 + nl) * 256 + lane + 64 * j] =
                (f16)((v[j] - mu) * rstd * gg[j] + bb[j]);
    }
}

// ------- merged: transpose+cast x [B,C,N]->[B,N,C] f16  AND  weight casts -------
__global__ __launch_bounds__(256) void xtw_kernel(const float* __restrict__ x,
                                                  f16* __restrict__ xT,
                                                  const float* __restrict__ Wq,
                                                  const float* __restrict__ Wkv,
                                                  const float* __restrict__ Wp,
                                                  f16* __restrict__ wq16,
                                                  f16* __restrict__ wkv16,
                                                  f16* __restrict__ wp16)
{
    int bid = blockIdx.x;
    if (bid < 512) {
        int b = bid >> 8, ct = (bid >> 5) & 7, nt = bid & 31;
        __shared__ float tile[32][33];
        int rr = threadIdx.x >> 5, j = threadIdx.x & 31;
        #pragma unroll
        for (int r = rr; r < 32; r += 8)
            tile[r][j] = x[((size_t)b * 256 + ct * 32 + r) * 1024 + nt * 32 + j];
        __syncthreads();
        #pragma unroll
        for (int r = rr; r < 32; r += 8)
            xT[((size_t)b * 1024 + nt * 32 + r) * 256 + ct * 32 + j] = (f16)tile[j][r];
    } else {
        int i = (bid - 512) * 256 + threadIdx.x;
        if (i < 65536) { wq16[i] = (f16)Wq[i]; wp16[i] = (f16)Wp[i]; }
        wkv16[i] = (f16)Wkv[i];
    }
}

// ---------------- merged Q and KV projections ----------------
__device__ __forceinline__ void gemm_tile(const f16* __restrict__ A, const f16* __restrict__ Bm,
                                          int row0, int ncol0, int l15, int lhi, f32x4 acc[4])
{
    for (int k0 = 0; k0 < 256; k0 += 32) {
        f16x8 a = *(const f16x8*)(A + (size_t)(row0 + l15) * 256 + k0 + lhi * 8);
        #pragma unroll
        for (int j = 0; j < 4; ++j) {
            f16x8 bf = *(const f16x8*)(Bm + (size_t)(ncol0 + j * 16 + l15) * 256 + k0 + lhi * 8);
            acc[j] = __builtin_amdgcn_mfma_f32_16x16x32_f16(a, bf, acc[j], 0, 0, 0);
        }
    }
}

__global__ __launch_bounds__(256) void qkv_kernel(const f16* __restrict__ xT,
                                                  const f16* __restrict__ yfln,
                                                  const f16* __restrict__ wq16,
                                                  const f16* __restrict__ wkv16,
                                                  f16* __restrict__ q16,
                                                  f16* __restrict__ k16,
                                                  f16* __restrict__ vT16)
{
    int w = threadIdx.x >> 6, lane = threadIdx.x & 63;
    int l15 = lane & 15, lhi = lane >> 4;
    if (blockIdx.x < 128) {
        int mt = blockIdx.x >> 2, nt = blockIdx.x & 3;
        int row0 = mt * 64 + w * 16;
        f32x4 acc[4] = {};
        gemm_tile(xT, wq16, row0, nt * 64, l15, lhi, acc);
        #pragma unroll
        for (int j = 0; j < 4; ++j) {
            int col = nt * 64 + j * 16 + l15;
            int h = col >> 5, d = col & 31;
            #pragma unroll
            for (int r = 0; r < 4; ++r) {
                int row = row0 + 4 * lhi + r;
                int b = row >> 10, n = row & 1023;
                q16[(((size_t)(b * 8 + h)) * 1024 + n) * 32 + d] = (f16)(acc[j][r] * ATT_SCALE);
            }
        }
    } else {
        int bid = blockIdx.x - 128;
        int mt = bid >> 3, nt = bid & 7;
        int row0 = mt * 64 + w * 16;
        f32x4 acc[4] = {};
        gemm_tile(yfln, wkv16, row0, nt * 64, l15, lhi, acc);
        #pragma unroll
        for (int j = 0; j < 4; ++j) {
            int col = nt * 64 + j * 16 + l15;
            #pragma unroll
            for (int r = 0; r < 4; ++r) {
                int row = row0 + 4 * lhi + r;
                int b = row >> 10, n = row & 1023;
                float v = acc[j][r];
                if (col < 256) {
                    int h = col >> 5, d = col & 31;
                    k16[(((size_t)(b * 8 + h)) * 1024 + n) * 32 + d] = (f16)v;
                } else {
                    int c2 = col - 256, h = c2 >> 5, d = c2 & 31;
                    vT16[(((size_t)(b * 8 + h)) * 32 + d) * 1024 + n] = (f16)v;
                }
            }
        }
    }
}

// ------- interleaved dual exact-count pivot search (T1: k=512, T2: k=341) -------
__device__ __forceinline__ void dual_thresh(const float* s, float mn, float mx,
                                            float& T1, float& T2)
{
    float lo1 = mn, hi1 = mx, lo2 = mn, hi2 = mx;
    bool d1 = false, d2 = false;
    T1 = mn; T2 = mn;
    for (int it = 0; it < 26; ++it) {
        if (d1 && d2) break;
        float m1 = 0.5f * (lo1 + hi1);
        float m2 = 0.5f * (lo2 + hi2);
        if (!d1 && !(m1 > lo1 && m1 < hi1)) d1 = true;
        if (!d2 && !(m2 > lo2 && m2 < hi2)) d2 = true;
        int c1 = 0, c2 = 0;
        #pragma unroll
        for (int i = 0; i < 16; ++i) {
            c1 += (int)__popcll(__ballot(s[i] >= m1));
            c2 += (int)__popcll(__ballot(s[i] >= m2));
        }
        if (!d1) {
            if (c1 == 512) { d1 = true; lo1 = m1; }
            else if (c1 > 512) lo1 = m1; else hi1 = m1;
        }
        if (!d2) {
            if (c2 == 341) { d2 = true; lo2 = m2; }
            else if (c2 > 341) lo2 = m2; else hi2 = m2;
        }
    }
    T1 = lo1;   // on exact hit lo==pivot; on fallback count(lo) >= k
    T2 = lo2;
}

// ---------------- fused attention, 8 waves/block ----------------
__global__ __launch_bounds__(512, 4) void attn_kernel(const f16* __restrict__ q16,
                                                      const f16* __restrict__ k16,
                                                      const f16* __restrict__ vT16,
                                                      const float* __restrict__ a1p,
                                                      const float* __restrict__ a2p,
                                                      f16* __restrict__ oat)
{
    __shared__ float Sb[16 * 1024];      // 64 KB, col-swizzled
    int bid = blockIdx.x;
    int bh = bid >> 6, rb = bid & 63;
    int row0 = rb * 16;
    int w = threadIdx.x >> 6, lane = threadIdx.x & 63;   // w in [0,8)
    int l15 = lane & 15, lhi = lane >> 4;
    const f16* Qb = q16 + (size_t)bh * 32768;
    const f16* Kb = k16 + (size_t)bh * 32768;
    const f16* Vb = vT16 + (size_t)bh * 32768;

    // phase 1: S = Q K^T ; wave w covers cols [w*128, w*128+128)
    {
        f16x8 a = *(const f16x8*)(Qb + (size_t)(row0 + l15) * 32 + lhi * 8);
        #pragma unroll
        for (int j = 0; j < 8; ++j) {
            int c0 = w * 128 + j * 16;
            f16x8 bf = *(const f16x8*)(Kb + (size_t)(c0 + l15) * 32 + lhi * 8);
            f32x4 z = {0.f, 0.f, 0.f, 0.f};
            f32x4 d = __builtin_amdgcn_mfma_f32_16x16x32_f16(a, bf, z, 0, 0, 0);
            #pragma unroll
            for (int r = 0; r < 4; ++r) {
                int rw = 4 * lhi + r;
                Sb[rw * 1024 + ((c0 + l15) ^ ((rw & 7) << 2))] = d[r];
            }
        }
    }
    __syncthreads();

    // phase 2: per-row thresholds + combined softmax weights (2 rows per wave)
    float c_a1 = a1p[0], c_a2 = a2p[0];
    #pragma unroll
    for (int rr = 0; rr < 2; ++rr) {
        int r = w * 2 + rr;
        int sw = (r & 7) << 2;
        float s[16];
        #pragma unroll
        for (int i = 0; i < 16; ++i) s[i] = Sb[r * 1024 + ((lane + 64 * i) ^ sw)];
        float mx = s[0], mn = s[0];
        #pragma unroll
        for (int i = 1; i < 16; ++i) { mx = fmaxf(mx, s[i]); mn = fminf(mn, s[i]); }
        #pragma unroll
        for (int off = 32; off; off >>= 1) {
            mx = fmaxf(mx, __shfl_xor(mx, off));
            mn = fminf(mn, __shfl_xor(mn, off));
        }
        float T1, T2;
        dual_thresh(s, mn, mx, T1, T2);
        float l1 = 0.f, l2 = 0.f;
        #pragma unroll
        for (int i = 0; i < 16; ++i) {
            float e = __expf(s[i] - mx);
            if (s[i] >= T1) l1 += e;
            if (s[i] >= T2) l2 += e;
        }
        #pragma unroll
        for (int off = 32; off; off >>= 1) { l1 += __shfl_xor(l1, off); l2 += __shfl_xor(l2, off); }
        float c1 = c_a1 / l1, c2 = c_a2 / l2;
        #pragma unroll
        for (int i = 0; i < 16; ++i) {
            float e = __expf(s[i] - mx);
            float wt = (s[i] >= T1 ? c1 : 0.f) + (s[i] >= T2 ? c2 : 0.f);
            Sb[r * 1024 + ((lane + 64 * i) ^ sw)] = e * wt;
        }
    }
    __syncthreads();

    // phase 3: out = W V, m-range split across 8 waves (128 m each)
    f32x4 acc0 = {}, acc1 = {};
    int swl = (l15 & 7) << 2;
    #pragma unroll
    for (int ks = 0; ks < 4; ++ks) {
        int m0 = w * 128 + ks * 32 + lhi * 8;
        float4 ch0 = *(const float4*)&Sb[l15 * 1024 + ((m0)     ^ swl)];
        float4 ch1 = *(const float4*)&Sb[l15 * 1024 + ((m0 + 4) ^ swl)];
        f16x8 af;
        af[0] = (f16)ch0.x; af[1] = (f16)ch0.y; af[2] = (f16)ch0.z; af[3] = (f16)ch0.w;
        af[4] = (f16)ch1.x; af[5] = (f16)ch1.y; af[6] = (f16)ch1.z; af[7] = (f16)ch1.w;
        f16x8 b0 = *(const f16x8*)(Vb + (size_t)(l15) * 1024 + m0);
        f16x8 b1 = *(const f16x8*)(Vb + (size_t)(16 + l15) * 1024 + m0);
        acc0 = __builtin_amdgcn_mfma_f32_16x16x32_f16(af, b0, acc0, 0, 0, 0);
        acc1 = __builtin_amdgcn_mfma_f32_16x16x32_f16(af, b1, acc1, 0, 0, 0);
    }
    __syncthreads();
    #pragma unroll
    for (int r = 0; r < 4; ++r) {
        int rw = 4 * lhi + r;
        Sb[w * 512 + rw * 32 + l15]      = acc0[r];
        Sb[w * 512 + rw * 32 + 16 + l15] = acc1[r];
    }
    __syncthreads();
    int b = bh >> 3, h = bh & 7;
    {
        int o = threadIdx.x;             // 512 threads, 512 outputs
        int r = o >> 5, d = o & 31;
        float v = 0.f;
        #pragma unroll
        for (int ww = 0; ww < 8; ++ww) v += Sb[ww * 512 + o];
        oat[((size_t)b * 1024 + row0 + r) * 256 + h * 32 + d] = (f16)v;
    }
}

// ---------------- output projection + bias, LDS-transposed coalesced writes ---------
__global__ __launch_bounds__(256) void projgemm_kernel(const f16* __restrict__ A,
                                                       const f16* __restrict__ Bm,
                                                       const float* __restrict__ bias,
                                                       float* __restrict__ out)
{
    __shared__ float tile[64][65];
    int mt = blockIdx.x >> 2, nt = blockIdx.x & 3;
    int w = threadIdx.x >> 6, lane = threadIdx.x & 63;
    int l15 = lane & 15, lhi = lane >> 4;
    int row0 = mt * 64 + w * 16;
    f32x4 acc[4] = {};
    gemm_tile(A, Bm, row0, nt * 64, l15, lhi, acc);
    #pragma unroll
    for (int j = 0; j < 4; ++j) {
        int col_l = j * 16 + l15;
        float bv = bias[nt * 64 + col_l];
        #pragma unroll
        for (int r = 0; r < 4; ++r)
            tile[col_l][w * 16 + 4 * lhi + r] = acc[j][r] + bv;
    }
    __syncthreads();
    int b = (mt * 64) >> 10, n0 = (mt * 64) & 1023;
    int col_l = threadIdx.x >> 2, part = threadIdx.x & 3;
    size_t base = (size_t)b * 262144 + (size_t)(nt * 64 + col_l) * 1024 + n0 + part * 16;
    #pragma unroll
    for (int q = 0; q < 4; ++q) {
        float4 v;
        v.x = tile[col_l][part * 16 + q * 4 + 0];
        v.y = tile[col_l][part * 16 + q * 4 + 1];
        v.z = tile[col_l][part * 16 + q * 4 + 2];
        v.w = tile[col_l][part * 16 + q * 4 + 3];
        *(float4*)(out + base + q * 4) = v;
    }
}

extern "C" void kernel_launch(void* const* d_in, const int* in_sizes, int n_in,
                              void* d_out, int out_size, void* d_ws, size_t ws_size,
                              hipStream_t stream)
{
    const float* x     = (const float*)d_in[0];
    const float* y     = (const float*)d_in[1];
    const float* Wq    = (const float*)d_in[2];
    const float* Wkv   = (const float*)d_in[3];
    const float* Wproj = (const float*)d_in[4];
    const float* bproj = (const float*)d_in[5];
    const float* ln_g  = (const float*)d_in[6];
    const float* ln_b  = (const float*)d_in[7];
    const float* a1p   = (const float*)d_in[8];
    const float* a2p   = (const float*)d_in[9];
    float* out = (float*)d_out;

    char* wsb = (char*)d_ws;
    float* pooled = (float*)(wsb);                                   // 2 MB [b][c][n]
    f16* yfln  = (f16*)(wsb + ((size_t)2 << 20));                    // 1 MB
    f16* xT    = (f16*)(wsb + ((size_t)3 << 20));                    // 1 MB
    f16* wq16  = (f16*)(wsb + ((size_t)4 << 20));                    // 128 KB
    f16* wkv16 = (f16*)(wsb + ((size_t)4 << 20) + (128 << 10));      // 256 KB
    f16* wp16  = (f16*)(wsb + ((size_t)4 << 20) + (384 << 10));      // 128 KB
    f16* q16   = (f16*)(wsb + ((size_t)4 << 20) + (512 << 10));      // 1 MB
    f16* k16   = (f16*)(wsb + ((size_t)4 << 20) + (512 << 10) + ((size_t)1 << 20));
    f16* vT16  = (f16*)(wsb + ((size_t)4 << 20) + (512 << 10) + ((size_t)2 << 20));
    f16* oat   = (f16*)(wsb + ((size_t)4 << 20) + (512 << 10) + ((size_t)3 << 20));

    pool_kernel<<<512, 256, 0, stream>>>(y, pooled);
    ln_kernel<<<64, 256, 0, stream>>>(pooled, ln_g, ln_b, yfln);
    xtw_kernel<<<1024, 256, 0, stream>>>(x, xT, Wq, Wkv, Wproj, wq16, wkv16, wp16);
    qkv_kernel<<<384, 256, 0, stream>>>(xT, yfln, wq16, wkv16, q16, k16, vT16);
    attn_kernel<<<1024, 512, 0, stream>>>(q16, k16, vT16, a1p, a2p, oat);
    projgemm_kernel<<<128, 256, 0, stream>>>(oat, wp16, bproj, out);
}

// Round 3
// 74.338 us; speedup vs baseline: 1.7341x; 1.2457x over previous
//
#include <hip/hip_runtime.h>

typedef _Float16 f16;
typedef f16 f16x8 __attribute__((ext_vector_type(8)));
typedef float f32x4 __attribute__((ext_vector_type(4)));

constexpr float ATT_SCALE = 0.17677669529663687f; // 1/sqrt(32)

// ------- merged prep: avg-pool (bid<512) | x transpose (bid<1024) | weight cast -------
__global__ __launch_bounds__(256) void prep_kernel(const float* __restrict__ y,
                                                   float* __restrict__ pooled,
                                                   const float* __restrict__ x,
                                                   f16* __restrict__ xT,
                                                   const float* __restrict__ Wq,
                                                   const float* __restrict__ Wkv,
                                                   const float* __restrict__ Wp,
                                                   f16* __restrict__ wq16,
                                                   f16* __restrict__ wkv16,
                                                   f16* __restrict__ wp16)
{
    __shared__ float sh[1444];
    int bid = blockIdx.x, t = threadIdx.x;
    if (bid < 512) {
        float (*p)[38] = (float(*)[38])sh;
        const float* plane = y + (size_t)bid * 1024;
        for (int i = t; i < 38 * 38; i += 256) (&p[0][0])[i] = 0.f;
        __syncthreads();
        for (int i = t; i < 1024; i += 256) p[(i >> 5) + 3][(i & 31) + 3] = plane[i];
        __syncthreads();
        for (int i = t; i < 1024; i += 256) {
            int r = (i >> 5) + 3, cc = (i & 31) + 3;
            float s3 = 0.f;
            #pragma unroll
            for (int dr = -1; dr <= 1; ++dr)
                #pragma unroll
                for (int dc = -1; dc <= 1; ++dc) s3 += p[r + dr][cc + dc];
            float r5 = 0.f;
            #pragma unroll
            for (int dc = -2; dc <= 2; ++dc) r5 += p[r - 2][cc + dc] + p[r + 2][cc + dc];
            #pragma unroll
            for (int dr = -1; dr <= 1; ++dr) r5 += p[r + dr][cc - 2] + p[r + dr][cc + 2];
            float r7 = 0.f;
            #pragma unroll
            for (int dc = -3; dc <= 3; ++dc) r7 += p[r - 3][cc + dc] + p[r + 3][cc + dc];
            #pragma unroll
            for (int dr = -2; dr <= 2; ++dr) r7 += p[r + dr][cc - 3] + p[r + dr][cc + 3];
            float s5 = s3 + r5, s7 = s5 + r7;
            pooled[(size_t)bid * 1024 + i] =
                s3 * (1.f / 9.f) + s5 * (1.f / 25.f) + s7 * (1.f / 49.f);
        }
    } else if (bid < 1024) {
        float (*tile)[33] = (float(*)[33])sh;
        int id = bid - 512;
        int b = id >> 8, ct = (id >> 5) & 7, nt = id & 31;
        int rr = t >> 5, j = t & 31;
        #pragma unroll
        for (int r = rr; r < 32; r += 8)
            tile[r][j] = x[((size_t)b * 256 + ct * 32 + r) * 1024 + nt * 32 + j];
        __syncthreads();
        #pragma unroll
        for (int r = rr; r < 32; r += 8)
            xT[((size_t)b * 1024 + nt * 32 + r) * 256 + ct * 32 + j] = (f16)tile[j][r];
    } else {
        int i = (bid - 1024) * 256 + t;
        if (i < 65536) { wq16[i] = (f16)Wq[i]; wp16[i] = (f16)Wp[i]; }
        wkv16[i] = (f16)Wkv[i];
    }
}

// ---------------- transposing LayerNorm: pooled[b][c][n] -> yfln[b][n][c] f16 --------
__global__ __launch_bounds__(256) void ln_kernel(const float* __restrict__ pooled,
                                                 const float* __restrict__ g,
                                                 const float* __restrict__ bta,
                                                 f16* __restrict__ yfln)
{
    __shared__ float tile[256][33];
    int bid = blockIdx.x;                // b*32 + ntile
    int b = bid >> 5, n0 = (bid & 31) * 32;
    int t = threadIdx.x;
    int cpart = t & 7;
    #pragma unroll
    for (int r0 = 0; r0 < 8; ++r0) {
        int c = r0 * 32 + (t >> 3);
        float4 v = *(const float4*)(pooled + ((size_t)b * 256 + c) * 1024 + n0 + cpart * 4);
        tile[c][cpart * 4 + 0] = v.x;
        tile[c][cpart * 4 + 1] = v.y;
        tile[c][cpart * 4 + 2] = v.z;
        tile[c][cpart * 4 + 3] = v.w;
    }
    __syncthreads();
    int w = t >> 6, lane = t & 63;
    float gg[4], bb[4];
    #pragma unroll
    for (int j = 0; j < 4; ++j) { gg[j] = g[lane + 64 * j]; bb[j] = bta[lane + 64 * j]; }
    for (int nn = 0; nn < 8; ++nn) {
        int nl = w * 8 + nn;
        float v[4];
        float s = 0.f, s2 = 0.f;
        #pragma unroll
        for (int j = 0; j < 4; ++j) {
            v[j] = tile[lane + 64 * j][nl];
            s += v[j]; s2 += v[j] * v[j];
        }
        #pragma unroll
        for (int off = 32; off; off >>= 1) { s += __shfl_xor(s, off); s2 += __shfl_xor(s2, off); }
        float mu = s * (1.f / 256.f);
        float var = s2 * (1.f / 256.f) - mu * mu;
        float rstd = rsqrtf(var + 1e-5f);
        #pragma unroll
        for (int j = 0; j < 4; ++j)
            yfln[((size_t)b * 1024 + n0 + nl) * 256 + lane + 64 * j] =
                (f16)((v[j] - mu) * rstd * gg[j] + bb[j]);
    }
}

// ---------------- merged Q and KV projections ----------------
__device__ __forceinline__ void gemm_tile(const f16* __restrict__ A, const f16* __restrict__ Bm,
                                          int row0, int ncol0, int l15, int lhi, f32x4 acc[4])
{
    for (int k0 = 0; k0 < 256; k0 += 32) {
        f16x8 a = *(const f16x8*)(A + (size_t)(row0 + l15) * 256 + k0 + lhi * 8);
        #pragma unroll
        for (int j = 0; j < 4; ++j) {
            f16x8 bf = *(const f16x8*)(Bm + (size_t)(ncol0 + j * 16 + l15) * 256 + k0 + lhi * 8);
            acc[j] = __builtin_amdgcn_mfma_f32_16x16x32_f16(a, bf, acc[j], 0, 0, 0);
        }
    }
}

__global__ __launch_bounds__(256) void qkv_kernel(const f16* __restrict__ xT,
                                                  const f16* __restrict__ yfln,
                                                  const f16* __restrict__ wq16,
                                                  const f16* __restrict__ wkv16,
                                                  f16* __restrict__ q16,
                                                  f16* __restrict__ k16,
                                                  f16* __restrict__ vT16)
{
    int w = threadIdx.x >> 6, lane = threadIdx.x & 63;
    int l15 = lane & 15, lhi = lane >> 4;
    if (blockIdx.x < 128) {
        int mt = blockIdx.x >> 2, nt = blockIdx.x & 3;
        int row0 = mt * 64 + w * 16;
        f32x4 acc[4] = {};
        gemm_tile(xT, wq16, row0, nt * 64, l15, lhi, acc);
        #pragma unroll
        for (int j = 0; j < 4; ++j) {
            int col = nt * 64 + j * 16 + l15;
            int h = col >> 5, d = col & 31;
            #pragma unroll
            for (int r = 0; r < 4; ++r) {
                int row = row0 + 4 * lhi + r;
                int b = row >> 10, n = row & 1023;
                q16[(((size_t)(b * 8 + h)) * 1024 + n) * 32 + d] = (f16)(acc[j][r] * ATT_SCALE);
            }
        }
    } else {
        int bid = blockIdx.x - 128;
        int mt = bid >> 3, nt = bid & 7;
        int row0 = mt * 64 + w * 16;
        f32x4 acc[4] = {};
        gemm_tile(yfln, wkv16, row0, nt * 64, l15, lhi, acc);
        #pragma unroll
        for (int j = 0; j < 4; ++j) {
            int col = nt * 64 + j * 16 + l15;
            #pragma unroll
            for (int r = 0; r < 4; ++r) {
                int row = row0 + 4 * lhi + r;
                int b = row >> 10, n = row & 1023;
                float v = acc[j][r];
                if (col < 256) {
                    int h = col >> 5, d = col & 31;
                    k16[(((size_t)(b * 8 + h)) * 1024 + n) * 32 + d] = (f16)v;
                } else {
                    int c2 = col - 256, h = c2 >> 5, d = c2 & 31;
                    vT16[(((size_t)(b * 8 + h)) * 32 + d) * 1024 + n] = (f16)v;
                }
            }
        }
    }
}

// ---------------- fused attention v3: 16 waves, histogram top-k select ----------------
__global__ __launch_bounds__(1024, 8) void attn_kernel(const f16* __restrict__ q16,
                                                       const f16* __restrict__ k16,
                                                       const f16* __restrict__ vT16,
                                                       const float* __restrict__ a1p,
                                                       const float* __restrict__ a2p,
                                                       f16* __restrict__ oat)
{
    __shared__ float Sb[16 * 1024];      // 64 KB, col-swizzled
    __shared__ int hist[16][256];        // 16 KB
    int bid = blockIdx.x;
    int bh = bid >> 6, rb = bid & 63;
    int row0 = rb * 16;
    int w = threadIdx.x >> 6, lane = threadIdx.x & 63;   // w in [0,16)
    int l15 = lane & 15, lhi = lane >> 4;
    const f16* Qb = q16 + (size_t)bh * 32768;
    const f16* Kb = k16 + (size_t)bh * 32768;
    const f16* Vb = vT16 + (size_t)bh * 32768;

    // phase 1: S = Q K^T ; wave w covers cols [w*64, w*64+64)
    {
        f16x8 a = *(const f16x8*)(Qb + (size_t)(row0 + l15) * 32 + lhi * 8);
        #pragma unroll
        for (int j = 0; j < 4; ++j) {
            int c0 = w * 64 + j * 16;
            f16x8 bf = *(const f16x8*)(Kb + (size_t)(c0 + l15) * 32 + lhi * 8);
            f32x4 z = {0.f, 0.f, 0.f, 0.f};
            f32x4 d = __builtin_amdgcn_mfma_f32_16x16x32_f16(a, bf, z, 0, 0, 0);
            #pragma unroll
            for (int r = 0; r < 4; ++r) {
                int rw = 4 * lhi + r;
                Sb[rw * 1024 + ((c0 + l15) ^ ((rw & 7) << 2))] = d[r];
            }
        }
    }
    // zero own-wave histogram (no cross-wave use)
    #pragma unroll
    for (int i = 0; i < 4; ++i) hist[w][lane + 64 * i] = 0;
    __syncthreads();

    // phase 2: wave w handles row w
    float c_a1 = a1p[0], c_a2 = a2p[0];
    int r = w, sw = (r & 7) << 2;
    float s[16];
    #pragma unroll
    for (int i = 0; i < 16; ++i) s[i] = Sb[r * 1024 + ((lane + 64 * i) ^ sw)];
    float mx = s[0], mn = s[0];
    #pragma unroll
    for (int i = 1; i < 16; ++i) { mx = fmaxf(mx, s[i]); mn = fminf(mn, s[i]); }
    #pragma unroll
    for (int off = 32; off; off >>= 1) {
        mx = fmaxf(mx, __shfl_xor(mx, off));
        mn = fminf(mn, __shfl_xor(mn, off));
    }
    float range = mx - mn;
    float inv = 255.0f / fmaxf(range, 1e-30f);
    #pragma unroll
    for (int i = 0; i < 16; ++i) {
        int bin = (int)((s[i] - mn) * inv);
        bin = bin < 0 ? 0 : (bin > 255 ? 255 : bin);
        atomicAdd(&hist[w][bin], 1);
    }
    // wave-parallel suffix count over 256 bins (4 per lane)
    int4 h4 = *(const int4*)&hist[w][lane * 4];
    int lsum = h4.x + h4.y + h4.z + h4.w;
    int acc = lsum;
    #pragma unroll
    for (int off = 1; off < 64; off <<= 1) {
        int o = __shfl_down(acc, off);
        if (lane + off < 64) acc += o;
    }
    int SA  = acc - lsum;            // S(4l+4)
    int Sv3 = SA + h4.w;             // S(4l+3)
    int Sv2 = Sv3 + h4.z;            // S(4l+2)
    int Sv1 = Sv2 + h4.y;            // S(4l+1)
    int Sv0 = Sv1 + h4.x;            // S(4l)
    int b1l = -1, b2l = -1;
    if (Sv0 >= 512 && Sv1 < 512) b1l = 4 * lane + 0;
    if (Sv1 >= 512 && Sv2 < 512) b1l = 4 * lane + 1;
    if (Sv2 >= 512 && Sv3 < 512) b1l = 4 * lane + 2;
    if (Sv3 >= 512 && SA  < 512) b1l = 4 * lane + 3;
    if (Sv0 >= 341 && Sv1 < 341) b2l = 4 * lane + 0;
    if (Sv1 >= 341 && Sv2 < 341) b2l = 4 * lane + 1;
    if (Sv2 >= 341 && Sv3 < 341) b2l = 4 * lane + 2;
    if (Sv3 >= 341 && SA  < 341) b2l = 4 * lane + 3;
    unsigned long long mb1 = __ballot(b1l >= 0);
    int b1 = __shfl(b1l, __ffsll(mb1) - 1);
    unsigned long long mb2 = __ballot(b2l >= 0);
    int b2 = __shfl(b2l, __ffsll(mb2) - 1);

    // dual exact-count bisection on +/-1-bin brackets
    float binw = range * (1.0f / 255.0f);
    float lo1 = mn + (float)(b1 - 1) * binw, hi1 = mn + (float)(b1 + 2) * binw;
    float lo2 = mn + (float)(b2 - 1) * binw, hi2 = mn + (float)(b2 + 2) * binw;
    bool d1 = false, d2 = false;
    for (int it = 0; it < 14; ++it) {
        if (d1 && d2) break;
        float m1 = 0.5f * (lo1 + hi1), m2 = 0.5f * (lo2 + hi2);
        if (!d1 && !(m1 > lo1 && m1 < hi1)) d1 = true;
        if (!d2 && !(m2 > lo2 && m2 < hi2)) d2 = true;
        int c1 = 0, c2 = 0;
        #pragma unroll
        for (int i = 0; i < 16; ++i) {
            c1 += (int)__popcll(__ballot(s[i] >= m1));
            c2 += (int)__popcll(__ballot(s[i] >= m2));
        }
        if (!d1) { if (c1 == 512) { d1 = true; lo1 = m1; } else if (c1 > 512) lo1 = m1; else hi1 = m1; }
        if (!d2) { if (c2 == 341) { d2 = true; lo2 = m2; } else if (c2 > 341) lo2 = m2; else hi2 = m2; }
    }
    float T1 = lo1, T2 = lo2;

    float l1 = 0.f, l2 = 0.f;
    #pragma unroll
    for (int i = 0; i < 16; ++i) {
        float e = __expf(s[i] - mx);
        if (s[i] >= T1) l1 += e;
        if (s[i] >= T2) l2 += e;
    }
    #pragma unroll
    for (int off = 32; off; off >>= 1) { l1 += __shfl_xor(l1, off); l2 += __shfl_xor(l2, off); }
    float c1 = c_a1 / l1, c2 = c_a2 / l2;
    #pragma unroll
    for (int i = 0; i < 16; ++i) {
        float e = __expf(s[i] - mx);
        float wt = (s[i] >= T1 ? c1 : 0.f) + (s[i] >= T2 ? c2 : 0.f);
        Sb[r * 1024 + ((lane + 64 * i) ^ sw)] = e * wt;
    }
    __syncthreads();

    // phase 3: out = W V, m-range split across 16 waves (64 m each)
    f32x4 acc0 = {}, acc1 = {};
    int swl = (l15 & 7) << 2;
    #pragma unroll
    for (int ks = 0; ks < 2; ++ks) {
        int m0 = w * 64 + ks * 32 + lhi * 8;
        float4 ch0 = *(const float4*)&Sb[l15 * 1024 + ((m0)     ^ swl)];
        float4 ch1 = *(const float4*)&Sb[l15 * 1024 + ((m0 + 4) ^ swl)];
        f16x8 af;
        af[0] = (f16)ch0.x; af[1] = (f16)ch0.y; af[2] = (f16)ch0.z; af[3] = (f16)ch0.w;
        af[4] = (f16)ch1.x; af[5] = (f16)ch1.y; af[6] = (f16)ch1.z; af[7] = (f16)ch1.w;
        f16x8 b0 = *(const f16x8*)(Vb + (size_t)(l15) * 1024 + m0);
        f16x8 b1v = *(const f16x8*)(Vb + (size_t)(16 + l15) * 1024 + m0);
        acc0 = __builtin_amdgcn_mfma_f32_16x16x32_f16(af, b0, acc0, 0, 0, 0);
        acc1 = __builtin_amdgcn_mfma_f32_16x16x32_f16(af, b1v, acc1, 0, 0, 0);
    }
    __syncthreads();
    #pragma unroll
    for (int rr2 = 0; rr2 < 4; ++rr2) {
        int rw = 4 * lhi + rr2;
        Sb[w * 512 + rw * 32 + l15]      = acc0[rr2];
        Sb[w * 512 + rw * 32 + 16 + l15] = acc1[rr2];
    }
    __syncthreads();
    int b = bh >> 3, h = bh & 7;
    int o = threadIdx.x;
    if (o < 512) {
        int rr = o >> 5, d = o & 31;
        float v = 0.f;
        #pragma unroll
        for (int ww = 0; ww < 16; ++ww) v += Sb[ww * 512 + o];
        oat[((size_t)b * 1024 + row0 + rr) * 256 + h * 32 + d] = (f16)v;
    }
}

// ---------------- output projection + bias, LDS-transposed coalesced writes ---------
__global__ __launch_bounds__(256) void projgemm_kernel(const f16* __restrict__ A,
                                                       const f16* __restrict__ Bm,
                                                       const float* __restrict__ bias,
                                                       float* __restrict__ out)
{
    __shared__ float tile[64][65];
    int mt = blockIdx.x >> 2, nt = blockIdx.x & 3;
    int w = threadIdx.x >> 6, lane = threadIdx.x & 63;
    int l15 = lane & 15, lhi = lane >> 4;
    int row0 = mt * 64 + w * 16;
    f32x4 acc[4] = {};
    gemm_tile(A, Bm, row0, nt * 64, l15, lhi, acc);
    #pragma unroll
    for (int j = 0; j < 4; ++j) {
        int col_l = j * 16 + l15;
        float bv = bias[nt * 64 + col_l];
        #pragma unroll
        for (int r = 0; r < 4; ++r)
            tile[col_l][w * 16 + 4 * lhi + r] = acc[j][r] + bv;
    }
    __syncthreads();
    int b = (mt * 64) >> 10, n0 = (mt * 64) & 1023;
    int col_l = threadIdx.x >> 2, part = threadIdx.x & 3;
    size_t base = (size_t)b * 262144 + (size_t)(nt * 64 + col_l) * 1024 + n0 + part * 16;
    #pragma unroll
    for (int q = 0; q < 4; ++q) {
        float4 v;
        v.x = tile[col_l][part * 16 + q * 4 + 0];
        v.y = tile[col_l][part * 16 + q * 4 + 1];
        v.z = tile[col_l][part * 16 + q * 4 + 2];
        v.w = tile[col_l][part * 16 + q * 4 + 3];
        *(float4*)(out + base + q * 4) = v;
    }
}

extern "C" void kernel_launch(void* const* d_in, const int* in_sizes, int n_in,
                              void* d_out, int out_size, void* d_ws, size_t ws_size,
                              hipStream_t stream)
{
    const float* x     = (const float*)d_in[0];
    const float* y     = (const float*)d_in[1];
    const float* Wq    = (const float*)d_in[2];
    const float* Wkv   = (const float*)d_in[3];
    const float* Wproj = (const float*)d_in[4];
    const float* bproj = (const float*)d_in[5];
    const float* ln_g  = (const float*)d_in[6];
    const float* ln_b  = (const float*)d_in[7];
    const float* a1p   = (const float*)d_in[8];
    const float* a2p   = (const float*)d_in[9];
    float* out = (float*)d_out;

    char* wsb = (char*)d_ws;
    float* pooled = (float*)(wsb);                                   // 2 MB [b][c][n]
    f16* yfln  = (f16*)(wsb + ((size_t)2 << 20));                    // 1 MB
    f16* xT    = (f16*)(wsb + ((size_t)3 << 20));                    // 1 MB
    f16* wq16  = (f16*)(wsb + ((size_t)4 << 20));                    // 128 KB
    f16* wkv16 = (f16*)(wsb + ((size_t)4 << 20) + (128 << 10));      // 256 KB
    f16* wp16  = (f16*)(wsb + ((size_t)4 << 20) + (384 << 10));      // 128 KB
    f16* q16   = (f16*)(wsb + ((size_t)4 << 20) + (512 << 10));      // 1 MB
    f16* k16   = (f16*)(wsb + ((size_t)4 << 20) + (512 << 10) + ((size_t)1 << 20));
    f16* vT16  = (f16*)(wsb + ((size_t)4 << 20) + (512 << 10) + ((size_t)2 << 20));
    f16* oat   = (f16*)(wsb + ((size_t)4 << 20) + (512 << 10) + ((size_t)3 << 20));

    prep_kernel<<<1536, 256, 0, stream>>>(y, pooled, x, xT, Wq, Wkv, Wproj,
                                          wq16, wkv16, wp16);
    ln_kernel<<<64, 256, 0, stream>>>(pooled, ln_g, ln_b, yfln);
    qkv_kernel<<<384, 256, 0, stream>>>(xT, yfln, wq16, wkv16, q16, k16, vT16);
    attn_kernel<<<1024, 1024, 0, stream>>>(q16, k16, vT16, a1p, a2p, oat);
    projgemm_kernel<<<128, 256, 0, stream>>>(oat, wp16, bproj, out);
}